// Round 2
// baseline (1806.733 us; speedup 1.0000x reference)
//
#include <hip/hip_runtime.h>
#include <math.h>

#define NVIEW 720
#define NDCT  1024
#define NZ    32
#define NX    512
#define NY    512

#define NR 24        // staged detector rows (16-wide x tile: i0 spread <= 22, +1 for i1)
#define RSTRIDE 20   // dwords per staged row (16 data + 4 pad; 80 B).
                     // Bank-group of chunk c in row r = (5r + c) mod 8, injective in
                     // r mod 8 -> only dr in {8,16} alias; measured ~0.75 cyc/read (ok).
                     // Do NOT swizzle chunks (R3 of prior session regressed).

typedef unsigned int uint;

#if __has_builtin(__builtin_amdgcn_fdot2)
#define USE_FDOT2 1
typedef _Float16 half2v __attribute__((ext_vector_type(2)));
#else
#define USE_FDOT2 0
#endif

// Round fp32 -> bf16 bits (RNE).
__device__ __forceinline__ uint f2bf_rne(float f) {
    uint u = __float_as_uint(f);
    return (u + 0x7fffu + ((u >> 16) & 1u)) >> 16;
}

// Packed word for (v, i, z):
//  fdot2 path:  lo16 = f16(g0 = p[i]), hi16 = f16(d = p[i+1]-p[i])
//               consumer: acc = v_dot2_f32_f16(word, {1.0, w}, acc)  -- 1 VALU/sample
//  fallback:    hi16 = dithered bf16(g0), lo16 = bf16(d)             -- 3 VALU/sample
__device__ __forceinline__ uint pack_word(float a, float b) {
#if USE_FDOT2
    union { _Float16 h[2]; uint u; } r;
    r.h[0] = (_Float16)a;         // g0 in low half
    r.h[1] = (_Float16)(b - a);   // d  in high half
    return r.u;
#else
    uint lo = f2bf_rne(b - a);
    uint u  = (f2bf_rne(a) << 16) | lo;
    uint up = u + 0x10000u, um = u - 0x10000u;
    float e0 = fabsf(__uint_as_float(u)  - a);
    float e1 = fabsf(__uint_as_float(up) - a);
    float e2 = fabsf(__uint_as_float(um) - a);
    if (e1 < e0) { u = up; e0 = e1; }
    if (e2 < e0) { u = um; }
    return u;
#endif
}

// packed[v][i][z], z contiguous (32 dw per (v,i)).
__global__ __launch_bounds__(64) void pack_kernel(const float* __restrict__ x,
                                                  uint* __restrict__ packed) {
    __shared__ uint tr[64 * 33];             // [i_local][z], stride 33 -> conflict-free
    const int l  = threadIdx.x;              // 0..63
    const int v  = blockIdx.x;               // 0..719
    const int ib = blockIdx.y * 64;          // i block base
    const bool last = (ib + 64 >= NDCT);
    const float* rowbase = x + (size_t)v * NDCT + ib;

    float pre = 0.0f;
    if (l < NZ && !last) pre = rowbase[(size_t)l * (NVIEW * NDCT) + 64];

    for (int z = 0; z < NZ; ++z) {
        const float* r = rowbase + (size_t)z * (NVIEW * NDCT);
        float a   = r[l];                    // coalesced 256B
        float a64 = __shfl(pre, z);
        float b   = __shfl(a, l + 1);
        if (l == 63) b = a64;                // neighbor across wave boundary
        tr[l * 33 + z] = pack_word(a, b);
    }
    __syncthreads();

    uint* obase = packed + ((size_t)v * NDCT + ib) * 32;
    #pragma unroll
    for (int it = 0; it < 8; ++it) {
        int c  = it * 64 + l;                // chunk 0..511; dst dword = 4c (coalesced)
        int il = c >> 3;
        int zc = (c & 7) * 4;
        uint4 w4;
        w4.x = tr[il * 33 + zc + 0];
        w4.y = tr[il * 33 + zc + 1];
        w4.z = tr[il * 33 + zc + 2];
        w4.w = tr[il * 33 + zc + 3];
        *(uint4*)(obase + (size_t)c * 4) = w4;
    }
}

#if USE_FDOT2
#define SAMP(A, zz, uu, WP, WF) do { \
    union { uint q; half2v h; } _c; _c.q = (uu); \
    A[zz] = __builtin_amdgcn_fdot2(_c.h, (WP), A[zz], false); \
} while (0)
#else
#define SAMP(A, zz, uu, WP, WF) do { \
    A[zz] += __uint_as_float(uu); \
    A[zz]  = fmaf((WF), __uint_as_float((uu) << 16), A[zz]); \
} while (0)
#endif

#define SAMPLE16(A, WP, WF) do { \
    SAMP(A, 0, q0.x, WP, WF); SAMP(A, 1, q0.y, WP, WF); \
    SAMP(A, 2, q0.z, WP, WF); SAMP(A, 3, q0.w, WP, WF); \
    SAMP(A, 4, q1.x, WP, WF); SAMP(A, 5, q1.y, WP, WF); \
    SAMP(A, 6, q1.z, WP, WF); SAMP(A, 7, q1.w, WP, WF); \
    SAMP(A, 8, q2.x, WP, WF); SAMP(A, 9, q2.y, WP, WF); \
    SAMP(A,10, q2.z, WP, WF); SAMP(A,11, q2.w, WP, WF); \
    SAMP(A,12, q3.x, WP, WF); SAMP(A,13, q3.y, WP, WF); \
    SAMP(A,14, q3.z, WP, WF); SAMP(A,15, q3.w, WP, WF); \
} while (0)

// 16x16 pixel tile, 128 threads (8x16): each thread owns pixels (x0, x0+1), 16 z.
// px0 is gathered from double-buffered LDS (85 B/cyc pipe); px1's row differs
// only when i1 != i0 (prob |c|, avg 0.64) and is then fetched from GLOBAL
// (L1/L2-resident: 3 KB/view/block working set), prefetched ONE VIEW AHEAD and
// merged with 16 cndmask. This splits gather traffic across the LDS and vmem
// pipes instead of serializing it all through LDS (R1 bottleneck: ~93% LDS).
// Schedule per view v:
//  [A1] tab[v+1] read + staging load st (full-view flight, as R1)
//  [C]  px0 ds_read x4 + SAMPLE16(acc0)
//  [D]  wait p (issued last iter), cndmask into q, SAMPLE16(acc1)
//  [A2] compute t/i/w/wp for v+1; masked global prefetch p for v+1 (~400cy flight)
//  [F]  publish st; one barrier (race-free double buffer)
__global__ __launch_bounds__(128, 4) void bp_lds(const uint* __restrict__ packed,
                                                 float* __restrict__ out) {
    __shared__ float4 tab[NVIEW];                           // 11520 B
    __shared__ __align__(16) uint stage[2][NR * RSTRIDE];   // 2 x 1920 B

    const int tid = threadIdx.y * 8 + threadIdx.x;          // 0..127
    const int g   = blockIdx.z;                              // z-group (16 z each)
    const float xf0 = (float)(int)(blockIdx.x * 16) - 255.5f;
    const float yf0 = (float)(int)(blockIdx.y * 16) - 255.5f;

    // Per-view cos/sin + block-uniform floor(t_min) folded as bval = 511.5 - imin.
    // bval fold perturbs t by <= 1 ULP(512) ~ 1.2e-4; trunc at 0 and NR slack absorb.
    for (int v = tid; v < NVIEW; v += 128) {
        float th = (float)v * (float)(M_PI / NVIEW);
        float s, c;
        sincosf(th, &s, &c);
        float b0 = fmaf(yf0, s, 511.5f);
        float b1 = fmaf(yf0 + 15.0f, s, 511.5f);
        float t00 = fmaf(xf0, c, b0);
        float t10 = fmaf(xf0 + 15.0f, c, b0);
        float t01 = fmaf(xf0, c, b1);
        float t11 = fmaf(xf0 + 15.0f, c, b1);
        int imin = (int)fminf(fminf(t00, t10), fminf(t01, t11));
        tab[v] = make_float4(c, s, 511.5f - (float)imin, __int_as_float(imin));
    }
    __syncthreads();

    const int x0 = blockIdx.x * 16 + threadIdx.x * 2;       // even
    const int y  = blockIdx.y * 16 + threadIdx.y;
    const float xf = (float)x0 - 255.5f;
    const float yf = (float)y  - 255.5f;

    float acc0[16], acc1[16];
    #pragma unroll
    for (int z = 0; z < 16; ++z) { acc0[z] = 0.0f; acc1[z] = 0.0f; }

    // Staging: NR rows x 16 dw = 96 x4-chunks over 2 waves (48 lanes each).
    const int  wv   = tid >> 6;
    const int  ln   = tid & 63;
    const bool sact = (ln < 48);
    const int  slot = wv * 48 + ln;          // 0..95
    const int  sr   = slot >> 2;             // staged row 0..23
    const int  sch  = slot & 3;              // 16B chunk 0..3
    const size_t sg_off = ((size_t)sr << 5) + (g << 4) + (sch << 2);   // global dw off
    const int  swr  = sr * RSTRIDE + (sch << 2);                        // LDS dw off

    // ---- prologue: set up view 0 ----
    float4 t4 = tab[0];
    uint4 st;
    if (sact) {
        st = *(const uint4*)(packed + ((size_t)__float_as_int(t4.w) << 5) + sg_off);
    }

    // carried per-view state (view v = "current")
    int   i0c, i1c, spoffc;
    float w0c, w1c;
#if USE_FDOT2
    half2v wp0c, wp1c;
#endif
    uint4 p0 = {0,0,0,0}, p1 = {0,0,0,0}, p2 = {0,0,0,0}, p3 = {0,0,0,0};

    {
        const float c = t4.x;
        float t0 = fmaf(xf, c, fmaf(yf, t4.y, t4.z));
        float t1 = t0 + c;
        i0c = (int)t0; i1c = (int)t1;
        w0c = t0 - (float)i0c; w1c = t1 - (float)i1c;
#if USE_FDOT2
        wp0c[0] = (_Float16)1.0f; wp0c[1] = (_Float16)w0c;
        wp1c[0] = (_Float16)1.0f; wp1c[1] = (_Float16)w1c;
#endif
        spoffc = i0c * RSTRIDE;
        if (i1c != i0c) {                    // masked global prefetch for view 0
            const uint* pp = packed + ((size_t)(__float_as_int(t4.w) + i1c) << 5)
                                    + ((size_t)g << 4);
            p0 = *(const uint4*)(pp);
            p1 = *(const uint4*)(pp + 4);
            p2 = *(const uint4*)(pp + 8);
            p3 = *(const uint4*)(pp + 12);
        }
        if (sact) *(uint4*)&stage[0][swr] = st;
    }
    __syncthreads();

    #pragma unroll 2
    for (int v = 0; v < NVIEW; ++v) {
        // [A1] early: next-view tab read + staging load (full-view flight)
        float4 t4n = t4;
        if (v + 1 < NVIEW) t4n = tab[v + 1];
        if (sact && v + 1 < NVIEW) {
            st = *(const uint4*)(packed + ((size_t)(v + 1) << 15)
                                 + ((size_t)__float_as_int(t4n.w) << 5) + sg_off);
        }

        // [C] px0 gather: 4x b128 off one base (imm offsets 0/64/128/192 B)
        const uint* sp = stage[v & 1] + spoffc;
        uint4 q0 = *(const uint4*)(sp);
        uint4 q1 = *(const uint4*)(sp + 4);
        uint4 q2 = *(const uint4*)(sp + 8);
        uint4 q3 = *(const uint4*)(sp + 12);

        SAMPLE16(acc0, wp0c, w0c);

        // [D] merge prefetched px1 row (global) where it differs from px0 row;
        // lanes with i1==i0 keep q = px0 row, which is exactly px1's row.
        {
            const bool m = (i1c != i0c);
            q0.x = m ? p0.x : q0.x; q0.y = m ? p0.y : q0.y;
            q0.z = m ? p0.z : q0.z; q0.w = m ? p0.w : q0.w;
            q1.x = m ? p1.x : q1.x; q1.y = m ? p1.y : q1.y;
            q1.z = m ? p1.z : q1.z; q1.w = m ? p1.w : q1.w;
            q2.x = m ? p2.x : q2.x; q2.y = m ? p2.y : q2.y;
            q2.z = m ? p2.z : q2.z; q2.w = m ? p2.w : q2.w;
            q3.x = m ? p3.x : q3.x; q3.y = m ? p3.y : q3.y;
            q3.z = m ? p3.z : q3.z; q3.w = m ? p3.w : q3.w;
        }

        SAMPLE16(acc1, wp1c, w1c);

        // [A2] compute next view's t/i/w and issue its masked px1 prefetch
        if (v + 1 < NVIEW) {
            const float cn = t4n.x;
            float t0n = fmaf(xf, cn, fmaf(yf, t4n.y, t4n.z));
            float t1n = t0n + cn;
            int i0n = (int)t0n, i1n = (int)t1n;
            float w0n = t0n - (float)i0n, w1n = t1n - (float)i1n;
#if USE_FDOT2
            half2v wp0n, wp1n;
            wp0n[0] = (_Float16)1.0f; wp0n[1] = (_Float16)w0n;
            wp1n[0] = (_Float16)1.0f; wp1n[1] = (_Float16)w1n;
#endif
            if (i1n != i0n) {
                const uint* pp = packed + ((size_t)(v + 1) << 15)
                                 + ((size_t)(__float_as_int(t4n.w) + i1n) << 5)
                                 + ((size_t)g << 4);
                p0 = *(const uint4*)(pp);
                p1 = *(const uint4*)(pp + 4);
                p2 = *(const uint4*)(pp + 8);
                p3 = *(const uint4*)(pp + 12);
            }
            i0c = i0n; i1c = i1n; w0c = w0n; w1c = w1n;
#if USE_FDOT2
            wp0c = wp0n; wp1c = wp1n;
#endif
            spoffc = i0n * RSTRIDE;
        }

        // [F] publish view v+1 stage (vmcnt waits only up to st, issued at [A1])
        if (sact && v + 1 < NVIEW) *(uint4*)&stage[(v + 1) & 1][swr] = st;
        // [G] one barrier per view: orders iter-(v+1) writes of a buffer after
        // all iter-v reads of it -> race-free double buffer
        __syncthreads();
        t4 = t4n;
    }

    const float scale = 0.0043633231299858236f;  // pi / 720
    #pragma unroll
    for (int lz = 0; lz < 16; ++lz) {
        float2 o = make_float2(acc0[lz] * scale, acc1[lz] * scale);
        *(float2*)(out + (((size_t)(g * 16 + lz)) * NY + y) * NX + x0) = o;
    }
}

// Fallback (ws too small for packed array): direct fp32, two loads per sample.
__global__ __launch_bounds__(256) void bp_direct(const float* __restrict__ xin,
                                                 float* __restrict__ out) {
    __shared__ float2 cs[NVIEW];
    int lt = threadIdx.y * 64 + threadIdx.x;
    for (int v = lt; v < NVIEW; v += 256) {
        float th = (float)v * (float)(M_PI / NVIEW);
        float s, c;
        sincosf(th, &s, &c);
        cs[v] = make_float2(c, s);
    }
    __syncthreads();

    int x = blockIdx.x * 64 + threadIdx.x;
    int y = blockIdx.y * 4 + threadIdx.y;
    float xf = (float)x - 255.5f;
    float yf = (float)y - 255.5f;

    float acc[NZ];
    #pragma unroll
    for (int z = 0; z < NZ; ++z) acc[z] = 0.0f;

    for (int v = 0; v < NVIEW; ++v) {
        float2 a = cs[v];
        float t  = fmaf(xf, a.x, fmaf(yf, a.y, 511.5f));
        int   i0 = (int)t;
        float w  = t - (float)i0;
        const float* p = xin + (size_t)v * NDCT + i0;
        #pragma unroll
        for (int z = 0; z < NZ; ++z) {
            float g0 = p[(size_t)z * NVIEW * NDCT];
            float g1 = p[(size_t)z * NVIEW * NDCT + 1];
            acc[z] += fmaf(w, g1 - g0, g0);
        }
    }

    const float scale = 0.0043633231299858236f;
    #pragma unroll
    for (int z = 0; z < NZ; ++z) {
        out[((size_t)z * NY + y) * NX + x] = acc[z] * scale;
    }
}

extern "C" void kernel_launch(void* const* d_in, const int* in_sizes, int n_in,
                              void* d_out, int out_size, void* d_ws, size_t ws_size,
                              hipStream_t stream) {
    const float* x = (const float*)d_in[0];
    float* out = (float*)d_out;

    const size_t packed_bytes = (size_t)NVIEW * NDCT * NZ * sizeof(uint);  // 94.4 MB

    if (ws_size >= packed_bytes) {
        uint* packed = (uint*)d_ws;
        pack_kernel<<<dim3(NVIEW, NDCT / 64), 64, 0, stream>>>(x, packed);
        bp_lds<<<dim3(NX / 16, NY / 16, 2), dim3(8, 16), 0, stream>>>(packed, out);
    } else {
        bp_direct<<<dim3(NX / 64, NY / 4), dim3(64, 4), 0, stream>>>(x, out);
    }
}

// Round 3
// 761.936 us; speedup vs baseline: 2.3712x; 2.3712x over previous
//
#include <hip/hip_runtime.h>
#include <math.h>

#define NVIEW 720
#define NDCT  1024
#define NZ    32
#define NX    512
#define NY    512

#define NR 24        // staged detector rows (16x16 tile: i spread <= 22, +1 for i+1)
#define RSTRIDE 20   // dwords per staged row (16 data + 4 pad; 80 B).
                     // Bank-group of chunk c in row r = (5r + c) mod 8, injective in
                     // r mod 8 -> only dr in {8,16} alias; measured ~0.75 cyc/read (ok).
                     // Do NOT swizzle chunks (prior session: XOR swizzle regressed).

typedef unsigned int uint;

#if __has_builtin(__builtin_amdgcn_fdot2)
#define USE_FDOT2 1
typedef _Float16 half2v __attribute__((ext_vector_type(2)));
#else
#define USE_FDOT2 0
#endif

// Round fp32 -> bf16 bits (RNE).
__device__ __forceinline__ uint f2bf_rne(float f) {
    uint u = __float_as_uint(f);
    return (u + 0x7fffu + ((u >> 16) & 1u)) >> 16;
}

// Packed word for (v, i, z):
//  fdot2 path:  lo16 = f16(g0 = p[i]), hi16 = f16(d = p[i+1]-p[i])
//               consumer: acc = v_dot2_f32_f16(word, {1.0, w}, acc)  -- 1 VALU/sample
//  fallback:    hi16 = dithered bf16(g0), lo16 = bf16(d)             -- 3 VALU/sample
__device__ __forceinline__ uint pack_word(float a, float b) {
#if USE_FDOT2
    union { _Float16 h[2]; uint u; } r;
    r.h[0] = (_Float16)a;         // g0 in low half
    r.h[1] = (_Float16)(b - a);   // d  in high half
    return r.u;
#else
    uint lo = f2bf_rne(b - a);
    uint u  = (f2bf_rne(a) << 16) | lo;
    uint up = u + 0x10000u, um = u - 0x10000u;
    float e0 = fabsf(__uint_as_float(u)  - a);
    float e1 = fabsf(__uint_as_float(up) - a);
    float e2 = fabsf(__uint_as_float(um) - a);
    if (e1 < e0) { u = up; e0 = e1; }
    if (e2 < e0) { u = um; }
    return u;
#endif
}

// packed[v][i][z], z contiguous (32 dw per (v,i)).
__global__ __launch_bounds__(64) void pack_kernel(const float* __restrict__ x,
                                                  uint* __restrict__ packed) {
    __shared__ uint tr[64 * 33];             // [i_local][z], stride 33 -> conflict-free
    const int l  = threadIdx.x;              // 0..63
    const int v  = blockIdx.x;               // 0..719
    const int ib = blockIdx.y * 64;          // i block base
    const bool last = (ib + 64 >= NDCT);
    const float* rowbase = x + (size_t)v * NDCT + ib;

    float pre = 0.0f;
    if (l < NZ && !last) pre = rowbase[(size_t)l * (NVIEW * NDCT) + 64];

    for (int z = 0; z < NZ; ++z) {
        const float* r = rowbase + (size_t)z * (NVIEW * NDCT);
        float a   = r[l];                    // coalesced 256B
        float a64 = __shfl(pre, z);
        float b   = __shfl(a, l + 1);
        if (l == 63) b = a64;                // neighbor across wave boundary
        tr[l * 33 + z] = pack_word(a, b);
    }
    __syncthreads();

    uint* obase = packed + ((size_t)v * NDCT + ib) * 32;
    #pragma unroll
    for (int it = 0; it < 8; ++it) {
        int c  = it * 64 + l;                // chunk 0..511; dst dword = 4c (coalesced)
        int il = c >> 3;
        int zc = (c & 7) * 4;
        uint4 w4;
        w4.x = tr[il * 33 + zc + 0];
        w4.y = tr[il * 33 + zc + 1];
        w4.z = tr[il * 33 + zc + 2];
        w4.w = tr[il * 33 + zc + 3];
        *(uint4*)(obase + (size_t)c * 4) = w4;
    }
}

#if USE_FDOT2
#define SAMP(A, zz, uu, WP, WF) do { \
    union { uint q; half2v h; } _c; _c.q = (uu); \
    A[zz] = __builtin_amdgcn_fdot2(_c.h, (WP), A[zz], false); \
} while (0)
#else
#define SAMP(A, zz, uu, WP, WF) do { \
    A[zz] += __uint_as_float(uu); \
    A[zz]  = fmaf((WF), __uint_as_float((uu) << 16), A[zz]); \
} while (0)
#endif

#define SAMPLE16(A, WP, WF) do { \
    SAMP(A, 0, q0.x, WP, WF); SAMP(A, 1, q0.y, WP, WF); \
    SAMP(A, 2, q0.z, WP, WF); SAMP(A, 3, q0.w, WP, WF); \
    SAMP(A, 4, q1.x, WP, WF); SAMP(A, 5, q1.y, WP, WF); \
    SAMP(A, 6, q1.z, WP, WF); SAMP(A, 7, q1.w, WP, WF); \
    SAMP(A, 8, q2.x, WP, WF); SAMP(A, 9, q2.y, WP, WF); \
    SAMP(A,10, q2.z, WP, WF); SAMP(A,11, q2.w, WP, WF); \
    SAMP(A,12, q3.x, WP, WF); SAMP(A,13, q3.y, WP, WF); \
    SAMP(A,14, q3.z, WP, WF); SAMP(A,15, q3.w, WP, WF); \
} while (0)

// Divergent masked gather: inactive lanes keep prior q (their correct row).
#define GATHER(SB, IR) do { \
    const uint* _sp = (SB) + (IR) * RSTRIDE; \
    q0 = *(const uint4*)(_sp); \
    q1 = *(const uint4*)(_sp + 4); \
    q2 = *(const uint4*)(_sp + 8); \
    q3 = *(const uint4*)(_sp + 12); \
} while (0)

// 16x16 pixel tile, ONE WAVE (64 threads), each thread owns a 2x2 pixel quad
// x{x0,x0+1} x y{y0,y0+1} x 16 z. The quad's detector rows {t, t+c, t+s, t+c+s}
// are walked as a chain with masked reloads (R1-proven pattern, no scratch):
// expected gathers = 1 + 2*min(|c|,|s|) + max = 2.65 avg per 64 samples vs
// R1's 1.64 per 32 -> -19% LDS gather traffic. Chain order picked per view by
// a wave-uniform branch. Single wave per block -> NO barriers at all: LDS ops
// are in-order per wave, so the double buffer is ordered by program order.
__global__ __launch_bounds__(64, 2) void bp_quad(const uint* __restrict__ packed,
                                                 float* __restrict__ out) {
    __shared__ float4 tab[NVIEW];                           // 11520 B
    __shared__ __align__(16) uint stage[2][NR * RSTRIDE];   // 2 x 1920 B

    const int tid = threadIdx.x;             // 0..63
    const int g   = blockIdx.z;              // z-group (16 z each)
    const float xf0 = (float)(int)(blockIdx.x * 16) - 255.5f;
    const float yf0 = (float)(int)(blockIdx.y * 16) - 255.5f;

    // Per-view cos/sin + block-uniform floor(t_min) folded as bval = 511.5 - imin.
    // bval fold perturbs t by <= 1 ULP(512); trunc at 0 and NR slack absorb it.
    for (int v = tid; v < NVIEW; v += 64) {
        float th = (float)v * (float)(M_PI / NVIEW);
        float s, c;
        sincosf(th, &s, &c);
        float b0 = fmaf(yf0, s, 511.5f);
        float b1 = fmaf(yf0 + 15.0f, s, 511.5f);
        float t00 = fmaf(xf0, c, b0);
        float t10 = fmaf(xf0 + 15.0f, c, b0);
        float t01 = fmaf(xf0, c, b1);
        float t11 = fmaf(xf0 + 15.0f, c, b1);
        int imin = (int)fminf(fminf(t00, t10), fminf(t01, t11));
        tab[v] = make_float4(c, s, 511.5f - (float)imin, __int_as_float(imin));
    }
    // no barrier: single wave, DS ops in order.

    const int qx = tid & 7, qy = tid >> 3;
    const int xo = blockIdx.x * 16 + qx * 2;
    const int yo = blockIdx.y * 16 + qy * 2;
    const float xf = (float)xo - 255.5f;
    const float yf = (float)yo - 255.5f;

    float a00[16], a10[16], a01[16], a11[16];
    #pragma unroll
    for (int z = 0; z < 16; ++z) { a00[z] = 0.0f; a10[z] = 0.0f; a01[z] = 0.0f; a11[z] = 0.0f; }

    // Staging: NR*4 = 96 x4-chunks over 64 lanes (lane does slot tid; lanes<32
    // also slot tid+64). Wave-static masks only -> no demotion risk.
    const int  sr0  = tid >> 2, sch0 = tid & 3;
    const size_t sg0 = ((size_t)sr0 << 5) + (g << 4) + (sch0 << 2);  // global dw off
    const int  ld0  = sr0 * RSTRIDE + (sch0 << 2);                   // LDS dw off
    const size_t sg1 = sg0 + ((size_t)16 << 5);                      // +16 rows
    const int  ld1  = ld0 + 16 * RSTRIDE;
    const bool s2   = (tid < 32);

    // ---- prologue: stage view 0 into buffer 0 ----
    float4 t4 = tab[0];
    {
        const uint* vb = packed + ((size_t)__float_as_int(t4.w) << 5);
        uint4 st0 = *(const uint4*)(vb + sg0);
        uint4 st1;
        if (s2) st1 = *(const uint4*)(vb + sg1);
        *(uint4*)&stage[0][ld0] = st0;
        if (s2) *(uint4*)&stage[0][ld1] = st1;
    }

    #pragma unroll 2
    for (int v = 0; v < NVIEW; ++v) {
        // [A] next-view tab read + staging loads (consumed at [F]; ~full view flight)
        float4 t4n = t4;
        if (v + 1 < NVIEW) t4n = tab[v + 1];
        uint4 st0, st1;
        if (v + 1 < NVIEW) {
            const uint* vb = packed + ((size_t)(v + 1) << 15)
                           + ((size_t)__float_as_int(t4n.w) << 5);
            st0 = *(const uint4*)(vb + sg0);
            if (s2) st1 = *(const uint4*)(vb + sg1);
        }

        const float c = t4.x, s = t4.y;
        float t00 = fmaf(xf, c, fmaf(yf, s, t4.z));     // t - imin, >= -1ulp
        float t10 = t00 + c;
        float t01 = t00 + s;
        float t11 = t10 + s;
        int   i00 = (int)t00, i10 = (int)t10, i01 = (int)t01, i11 = (int)t11;
        float w00 = t00 - (float)i00, w10 = t10 - (float)i10;
        float w01 = t01 - (float)i01, w11 = t11 - (float)i11;

#if USE_FDOT2
        half2v wp00, wp10, wp01, wp11;
        wp00[0] = (_Float16)1.0f; wp00[1] = (_Float16)w00;
        wp10[0] = (_Float16)1.0f; wp10[1] = (_Float16)w10;
        wp01[0] = (_Float16)1.0f; wp01[1] = (_Float16)w01;
        wp11[0] = (_Float16)1.0f; wp11[1] = (_Float16)w11;
#else
        const int wp00 = 0, wp10 = 0, wp01 = 0, wp11 = 0;  // unused tokens
#endif

        // [C] quad chain: full gather for px00, then masked reloads along a
        // snake whose first axis is the smaller-|slope| one (wave-uniform branch).
        const uint* sb = stage[v & 1];
        uint4 q0, q1, q2, q3;
        int ir = i00;
        GATHER(sb, ir);
        SAMPLE16(a00, wp00, w00);
        if (fabsf(c) <= fabsf(s)) {          // steps: +c, +s, -c
            if (i10 != ir) { ir = i10; GATHER(sb, ir); }
            SAMPLE16(a10, wp10, w10);
            if (i11 != ir) { ir = i11; GATHER(sb, ir); }
            SAMPLE16(a11, wp11, w11);
            if (i01 != ir) { ir = i01; GATHER(sb, ir); }
            SAMPLE16(a01, wp01, w01);
        } else {                             // steps: +s, +c, -s
            if (i01 != ir) { ir = i01; GATHER(sb, ir); }
            SAMPLE16(a01, wp01, w01);
            if (i11 != ir) { ir = i11; GATHER(sb, ir); }
            SAMPLE16(a11, wp11, w11);
            if (i10 != ir) { ir = i10; GATHER(sb, ir); }
            SAMPLE16(a10, wp10, w10);
        }

        // [F] publish view v+1 stage; in-order DS makes next iter's reads see it.
        if (v + 1 < NVIEW) {
            uint* pb = &stage[(v + 1) & 1][0];
            *(uint4*)(pb + ld0) = st0;
            if (s2) *(uint4*)(pb + ld1) = st1;
        }
        t4 = t4n;
    }

    const float scale = 0.0043633231299858236f;  // pi / 720
    #pragma unroll
    for (int lz = 0; lz < 16; ++lz) {
        size_t base = (((size_t)(g * 16 + lz)) * NY + yo) * NX + xo;
        *(float2*)(out + base)      = make_float2(a00[lz] * scale, a10[lz] * scale);
        *(float2*)(out + base + NX) = make_float2(a01[lz] * scale, a11[lz] * scale);
    }
}

// Fallback (ws too small for packed array): direct fp32, two loads per sample.
__global__ __launch_bounds__(256) void bp_direct(const float* __restrict__ xin,
                                                 float* __restrict__ out) {
    __shared__ float2 cs[NVIEW];
    int lt = threadIdx.y * 64 + threadIdx.x;
    for (int v = lt; v < NVIEW; v += 256) {
        float th = (float)v * (float)(M_PI / NVIEW);
        float s, c;
        sincosf(th, &s, &c);
        cs[v] = make_float2(c, s);
    }
    __syncthreads();

    int x = blockIdx.x * 64 + threadIdx.x;
    int y = blockIdx.y * 4 + threadIdx.y;
    float xf = (float)x - 255.5f;
    float yf = (float)y - 255.5f;

    float acc[NZ];
    #pragma unroll
    for (int z = 0; z < NZ; ++z) acc[z] = 0.0f;

    for (int v = 0; v < NVIEW; ++v) {
        float2 a = cs[v];
        float t  = fmaf(xf, a.x, fmaf(yf, a.y, 511.5f));
        int   i0 = (int)t;
        float w  = t - (float)i0;
        const float* p = xin + (size_t)v * NDCT + i0;
        #pragma unroll
        for (int z = 0; z < NZ; ++z) {
            float g0 = p[(size_t)z * NVIEW * NDCT];
            float g1 = p[(size_t)z * NVIEW * NDCT + 1];
            acc[z] += fmaf(w, g1 - g0, g0);
        }
    }

    const float scale = 0.0043633231299858236f;
    #pragma unroll
    for (int z = 0; z < NZ; ++z) {
        out[((size_t)z * NY + y) * NX + x] = acc[z] * scale;
    }
}

extern "C" void kernel_launch(void* const* d_in, const int* in_sizes, int n_in,
                              void* d_out, int out_size, void* d_ws, size_t ws_size,
                              hipStream_t stream) {
    const float* x = (const float*)d_in[0];
    float* out = (float*)d_out;

    const size_t packed_bytes = (size_t)NVIEW * NDCT * NZ * sizeof(uint);  // 94.4 MB

    if (ws_size >= packed_bytes) {
        uint* packed = (uint*)d_ws;
        pack_kernel<<<dim3(NVIEW, NDCT / 64), 64, 0, stream>>>(x, packed);
        bp_quad<<<dim3(NX / 16, NY / 16, 2), dim3(64), 0, stream>>>(packed, out);
    } else {
        bp_direct<<<dim3(NX / 64, NY / 4), dim3(64, 4), 0, stream>>>(x, out);
    }
}